// Round 21
// baseline (41.769 us; speedup 1.0000x reference)
//
#include <hip/hip_runtime.h>
#include <hip/hip_bf16.h>

typedef __attribute__((ext_vector_type(8))) short bf16x8;
typedef __attribute__((ext_vector_type(4))) float f32x4;
typedef __attribute__((ext_vector_type(4))) unsigned short u16x4;

#define B_NUM 2048
#define F_NUM 40
#define E_DIM 32
#define P_NUM 780
#define D_DIM 16
#define NT_FULL 45          // full 4x4 tiles (I<J)
#define NT_ALL  55          // + 10 diagonal tiles
#define LN_EPS 1e-3f

// workspace layout (bytes)
#define XB_OFF  0
#define XB_BYTES (F_NUM * 4 * B_NUM * 8 * 2)       // 5.2 MB packed bf16 x [f][e8][b][8]
#define HP_OFF  XB_BYTES                           // hpart bf16 [55][2048][16] = 3.6 MB

static __device__ __forceinline__ unsigned short f2b(float f) {
  unsigned u = __builtin_bit_cast(unsigned, f);
  u += 0x7fffu + ((u >> 16) & 1u);                 // round-to-nearest-even
  return (unsigned short)(u >> 16);
}
static __device__ __forceinline__ short f2bs(float f) { return (short)f2b(f); }
static __device__ __forceinline__ short fcvt(float f) {
  return (short)__bfloat16_as_ushort(__float2bfloat16(f));
}
static __device__ __forceinline__ float b2f(unsigned short u) {
  return __builtin_bit_cast(float, (unsigned)u << 16);
}

// ---------------------------------------------------------------------------
// Prep (x-pack only, unchanged): x -> packed bf16 [f][e8][b][8], b-minor.
__global__ __launch_bounds__(256) void xpack_kernel(
    const float* __restrict__ x, short* __restrict__ xbp) {
  const int u  = blockIdx.x * 256 + threadIdx.x;
  const int b  = u & (B_NUM - 1);
  const int fp = u >> 11;                          // 0..79: (f, e16-half)
  const int f  = fp >> 1;
  const float* src = x + ((size_t)b * F_NUM + f) * E_DIM + (fp & 1) * 16;
  const float4 v0 = *reinterpret_cast<const float4*>(src);
  const float4 v1 = *reinterpret_cast<const float4*>(src + 4);
  const float4 v2 = *reinterpret_cast<const float4*>(src + 8);
  const float4 v3 = *reinterpret_cast<const float4*>(src + 12);
  const int plane = f * 4 + (fp & 1) * 2;          // e8 plane index
  bf16x8 o0, o1;
  o0[0] = f2bs(v0.x); o0[1] = f2bs(v0.y); o0[2] = f2bs(v0.z); o0[3] = f2bs(v0.w);
  o0[4] = f2bs(v1.x); o0[5] = f2bs(v1.y); o0[6] = f2bs(v1.z); o0[7] = f2bs(v1.w);
  o1[0] = f2bs(v2.x); o1[1] = f2bs(v2.y); o1[2] = f2bs(v2.z); o1[3] = f2bs(v2.w);
  o1[4] = f2bs(v3.x); o1[5] = f2bs(v3.y); o1[6] = f2bs(v3.z); o1[7] = f2bs(v3.w);
  *reinterpret_cast<bf16x8*>(xbp + ((size_t)plane * B_NUM + b) * 8)       = o0;
  *reinterpret_cast<bf16x8*>(xbp + ((size_t)(plane + 1) * B_NUM + b) * 8) = o1;
}

// ---------------------------------------------------------------------------
// Tiled fused kernel: pair space split into 4x4 (i,j) tiles so each x row is
// reused by 4 pairs (L2 x-traffic 205 -> ~84 MB). Block = 128 batches x 1
// tile; wave (ph = batch-half, pv = pair-half) holds 2 xi rows + 4 xj rows
// in REGISTERS; the 8-pair loop is load-free (afrag via LDS, dw scalar).
//   MFMA1: t[fo,b] = W_p^T xi ; u = bf16(t * xj) is MFMA2's B-fragment;
//   MFMA2 (A = dw[p,d] bcast over k) does f-reduction AND dense fold.
// Cross-pv reduction in LDS; hpart[tile] bf16. grid (16, 55), block 256.
__global__ __launch_bounds__(256, 2) void fused_bilinear_dense_kernel(
    const float* __restrict__ W, const float* __restrict__ dw,
    const short* __restrict__ xbp, unsigned short* __restrict__ hpart) {
  __shared__ unsigned short wraw[16 * 1024];                     // 32 KB bf16 W [idx][e][f]
  __shared__ __align__(16) unsigned short afrag[16 * 2 * 512];   // 32 KB a-frags
  __shared__ float redbuf[4 * 64 * 16];                          // 16 KB cross-pv reduce

  const int tid  = threadIdx.x;
  const int lane = tid & 63, wv = tid >> 6;
  const int lhi = lane >> 4, llo = lane & 15;
  const int ph = wv >> 1;                          // batch half (0/1)
  const int pv = wv & 1;                           // pair half (0/1)
  const int bb = blockIdx.x * 128 + ph * 64;
  const int t  = blockIdx.y;

  // ---- decode tile t -> (I, J) ----
  int I, J;
  if (t < NT_FULL) {
    I = 0;
    while (9 * (I + 1) - (I + 1) * I / 2 <= t) ++I;
    J = I + 1 + (t - (9 * I - I * (I - 1) / 2));
  } else {
    I = t - NT_FULL; J = I;
  }
  const bool diag = (I == J);

  // ---- stage the tile's 16 W matrices (f32 -> bf16 LDS), one per pass ----
#pragma unroll
  for (int idx = 0; idx < 16; ++idx) {
    const int i = 4 * I + (idx >> 2), j = 4 * J + (idx & 3);
    if (j > i) {                                   // valid pair (always, if !diag)
      const int p = i * (79 - i) / 2 + (j - i - 1);
      const float4 v = *reinterpret_cast<const float4*>(
          W + (size_t)p * 1024 + tid * 4);
      u16x4 o;
      o[0] = f2b(v.x); o[1] = f2b(v.y); o[2] = f2b(v.z); o[3] = f2b(v.w);
      *reinterpret_cast<u16x4*>(&wraw[idx * 1024 + tid * 4]) = o;
    }
  }
  __syncthreads();

  // ---- build A-fragments (f-PERMUTED m-rows), wave wv builds idx wv*4+q ----
  // A-frag (16x16x32): lane l holds A[m=l&15][k=(l>>4)*8+t]; m -> fo =
  // (m>>2)*8+frag*4+(m&3), so C-row m=lhi*4+r maps to fo=lhi*8+frag*4+r.
#pragma unroll
  for (int q = 0; q < 4; ++q) {
    const int pl = wv * 4 + q;
#pragma unroll
    for (int frag = 0; frag < 2; ++frag) {
      const int fo = (llo >> 2) * 8 + frag * 4 + (llo & 3);
      bf16x8 v;
#pragma unroll
      for (int tt = 0; tt < 8; ++tt)
        v[tt] = (short)wraw[pl * 1024 + (lhi * 8 + tt) * E_DIM + fo];
      *reinterpret_cast<bf16x8*>(&afrag[(pl * 2 + frag) * 512 + lane * 8]) = v;
    }
  }
  __syncthreads();

  int off[4];                                      // packed-table lane offsets
#pragma unroll
  for (int nt = 0; nt < 4; ++nt)
    off[nt] = (lhi * B_NUM + bb + nt * 16 + llo) * 8;
#define XB8(f, o) (*reinterpret_cast<const bf16x8*>(xbp + (size_t)(f) * 65536 + (o)))

  // ---- register-resident x fragments: 2 xi rows + 4 xj rows ----
  bf16x8 bxi[2][4], bxj[4][4];
#pragma unroll
  for (int s = 0; s < 2; ++s) {
    const int irow = 4 * I + pv * 2 + s;
#pragma unroll
    for (int nt = 0; nt < 4; ++nt) bxi[s][nt] = XB8(irow, off[nt]);
  }
#pragma unroll
  for (int b = 0; b < 4; ++b) {
    const int jrow = 4 * J + b;
#pragma unroll
    for (int nt = 0; nt < 4; ++nt) bxj[b][nt] = XB8(jrow, off[nt]);
  }
#undef XB8

  f32x4 acc[4];
#pragma unroll
  for (int nt = 0; nt < 4; ++nt) acc[nt] = {0.f, 0.f, 0.f, 0.f};
  const f32x4 z = {0.f, 0.f, 0.f, 0.f};

  // ---- 8-pair loop, fully register/LDS-resident ----
#pragma unroll
  for (int s = 0; s < 2; ++s) {
    const int a = pv * 2 + s;
    const int i = 4 * I + a;
#pragma unroll
    for (int b = 0; b < 4; ++b) {
      const int j = 4 * J + b;
      if (diag && j <= i) continue;                // wave-uniform skip
      const int p   = i * (79 - i) / 2 + (j - i - 1);
      const int idx = a * 4 + b;

      const bf16x8 a0 = *reinterpret_cast<const bf16x8*>(
          &afrag[(idx * 2 + 0) * 512 + lane * 8]);
      const bf16x8 a1 = *reinterpret_cast<const bf16x8*>(
          &afrag[(idx * 2 + 1) * 512 + lane * 8]);
      const short dwb = fcvt(dw[p * D_DIM + llo]);

      __builtin_amdgcn_s_setprio(1);
      f32x4 c0[4], c1[4];
#pragma unroll
      for (int nt = 0; nt < 4; ++nt) {
        c0[nt] = __builtin_amdgcn_mfma_f32_16x16x32_bf16(a0, bxi[s][nt], z, 0, 0, 0);
        c1[nt] = __builtin_amdgcn_mfma_f32_16x16x32_bf16(a1, bxi[s][nt], z, 0, 0, 0);
      }
      bf16x8 a2;
#pragma unroll
      for (int tt = 0; tt < 8; ++tt) a2[tt] = dwb;
#pragma unroll
      for (int nt = 0; nt < 4; ++nt) {
        bf16x8 u;                                  // B-frag of MFMA2
#pragma unroll
        for (int tt = 0; tt < 4; ++tt) {
          u[tt]     = fcvt(c0[nt][tt] * b2f((unsigned short)bxj[b][nt][tt]));
          u[tt + 4] = fcvt(c1[nt][tt] * b2f((unsigned short)bxj[b][nt][tt + 4]));
        }
        acc[nt] = __builtin_amdgcn_mfma_f32_16x16x32_bf16(a2, u, acc[nt], 0, 0, 0);
      }
      __builtin_amdgcn_s_setprio(0);
    }
  }

  // ---- cross-pv reduction via LDS, then bf16 hpart write ----
  // lane holds (b = nt*16+llo, d = lhi*4+r) of its wave's partial h.
#pragma unroll
  for (int nt = 0; nt < 4; ++nt)
#pragma unroll
    for (int r = 0; r < 4; ++r)
      redbuf[wv * 1024 + (nt * 16 + llo) * 16 + lhi * 4 + r] = acc[nt][r];
  __syncthreads();

  {
    const int v0  = tid * 8;                       // 8 outputs per thread
    const int ph2 = v0 >> 10;                      // batch half
    const int q   = v0 & 1023;                     // (b_loc*16 + d)
    bf16x8 ov;
#pragma unroll
    for (int e = 0; e < 8; ++e) {
      const float val = redbuf[(ph2 * 2 + 0) * 1024 + q + e] +
                        redbuf[(ph2 * 2 + 1) * 1024 + q + e];
      ov[e] = f2bs(val);
    }
    *reinterpret_cast<bf16x8*>(
        hpart + (size_t)t * (B_NUM * D_DIM) + blockIdx.x * 2048 + ph2 * 1024 + q) = ov;
  }
}

// ---------------------------------------------------------------------------
// Final: sum 55 bf16 h-partials + bias, LayerNorm. grid 64, block 256;
// thread = (b, d-pair): one uint (2 bf16) per tile -> coalesced.
__global__ __launch_bounds__(256) void reduce_ln_kernel(
    const unsigned short* __restrict__ hpart, const float* __restrict__ bias,
    const float* __restrict__ gamma, const float* __restrict__ beta,
    float* __restrict__ out) {
  const int g  = blockIdx.x * 256 + threadIdx.x;
  const int b  = g >> 3;
  const int d2 = g & 7;                            // d = 2*d2, 2*d2+1
  const uint* hp = reinterpret_cast<const uint*>(hpart) + (size_t)b * 8 + d2;

  float h0 = bias[2 * d2], h1 = bias[2 * d2 + 1];
#pragma unroll 11
  for (int pc = 0; pc < NT_ALL; ++pc) {
    const uint v = hp[(size_t)pc * B_NUM * 8];
    h0 += b2f((unsigned short)v);
    h1 += b2f((unsigned short)(v >> 16));
  }

  float sum = h0 + h1;
  sum += __shfl_xor(sum, 1); sum += __shfl_xor(sum, 2); sum += __shfl_xor(sum, 4);
  const float mu = sum * (1.f / D_DIM);
  const float dv0 = h0 - mu, dv1 = h1 - mu;
  float v = dv0 * dv0 + dv1 * dv1;
  v += __shfl_xor(v, 1); v += __shfl_xor(v, 2); v += __shfl_xor(v, 4);
  const float rs = rsqrtf(v * (1.f / D_DIM) + LN_EPS);

  float2 o;
  o.x = dv0 * rs * gamma[2 * d2]     + beta[2 * d2];
  o.y = dv1 * rs * gamma[2 * d2 + 1] + beta[2 * d2 + 1];
  *reinterpret_cast<float2*>(out + (size_t)b * D_DIM + 2 * d2) = o;
}

extern "C" void kernel_launch(void* const* d_in, const int* in_sizes, int n_in,
                              void* d_out, int out_size, void* d_ws, size_t ws_size,
                              hipStream_t stream) {
  const float* x     = (const float*)d_in[0];
  const float* W     = (const float*)d_in[1];
  const float* dw    = (const float*)d_in[2];
  const float* db    = (const float*)d_in[3];
  const float* gamma = (const float*)d_in[4];
  const float* beta  = (const float*)d_in[5];
  float* out = (float*)d_out;

  short*          xbp   = (short*)((char*)d_ws + XB_OFF);
  unsigned short* hpart = (unsigned short*)((char*)d_ws + HP_OFF);

  xpack_kernel<<<640, 256, 0, stream>>>(x, xbp);

  dim3 gA(B_NUM / 128, NT_ALL);
  fused_bilinear_dense_kernel<<<gA, 256, 0, stream>>>(W, dw, xbp, hpart);

  reduce_ln_kernel<<<B_NUM * 8 / 256, 256, 0, stream>>>(hpart, db, gamma, beta, out);
}

// Round 22
// 29.533 us; speedup vs baseline: 1.4143x; 1.4143x over previous
//
#include <hip/hip_runtime.h>
#include <hip/hip_bf16.h>

typedef __attribute__((ext_vector_type(8))) short bf16x8;
typedef __attribute__((ext_vector_type(4))) float f32x4;
typedef __attribute__((ext_vector_type(4))) unsigned short u16x4;

#define B_NUM 2048
#define F_NUM 40
#define E_DIM 32
#define P_NUM 780
#define D_DIM 16
#define PC_N  65            // pair chunks
#define PC_SZ 12            // 65*12 = 780 exactly
#define LN_EPS 1e-3f

// workspace layout (bytes)
#define XB_OFF  0
#define XB_BYTES (F_NUM * 4 * B_NUM * 8 * 2)       // 5.2 MB packed bf16 x [f][e8][b][8]
#define HP_OFF  XB_BYTES                           // hpart bf16 [PC_N][B][D] = 4.25 MB

static __device__ __forceinline__ unsigned short f2b(float f) {
  unsigned u = __builtin_bit_cast(unsigned, f);
  u += 0x7fffu + ((u >> 16) & 1u);                 // round-to-nearest-even
  return (unsigned short)(u >> 16);
}
static __device__ __forceinline__ short f2bs(float f) { return (short)f2b(f); }
static __device__ __forceinline__ short fcvt(float f) {
  return (short)__bfloat16_as_ushort(__float2bfloat16(f));
}
static __device__ __forceinline__ float b2f(unsigned short u) {
  return __builtin_bit_cast(float, (unsigned)u << 16);
}

// ---------------------------------------------------------------------------
// xpack via LDS transpose: block = 8 batch rows.
//  phase 1: linear coalesced f32 reads (10 float4/thread, 100% line use),
//           bf16-convert into padded LDS [8][1288] (row pad spreads banks).
//  phase 2: emit packed planes: chunk c -> (plane = c>>3, b = c&7); 8
//           consecutive threads write 128 B contiguous per plane.
// Layout identical to prior xpack: xbp[(plane*B + b)*8 + e],
// plane = f*4 + e8, LDS offset plane*8+e = f*32 + e8*8 + e.
__global__ __launch_bounds__(256) void xpack_kernel(
    const float* __restrict__ x, short* __restrict__ xbp) {
  __shared__ unsigned short xs[8][1288];           // 20.6 KB
  const int tid = threadIdx.x;
  const int bb  = blockIdx.x * 8;
  const float* src = x + (size_t)bb * (F_NUM * E_DIM);

#pragma unroll
  for (int r = 0; r < 10; ++r) {
    const int k = r * 256 + tid;                   // float4 index, 2560/block
    const float4 v = *reinterpret_cast<const float4*>(src + (size_t)k * 4);
    const int row  = k / 320;                      // 320 float4 per row
    const int col4 = k - row * 320;
    u16x4 o;
    o[0] = f2b(v.x); o[1] = f2b(v.y); o[2] = f2b(v.z); o[3] = f2b(v.w);
    *reinterpret_cast<u16x4*>(&xs[row][col4 * 4]) = o;
  }
  __syncthreads();

#pragma unroll
  for (int r = 0; r < 5; ++r) {
    const int c     = r * 256 + tid;               // 1280 chunks/block
    const int plane = c >> 3;                      // 0..159
    const int b     = c & 7;
    const bf16x8 v = *reinterpret_cast<const bf16x8*>(&xs[b][plane * 8]);
    *reinterpret_cast<bf16x8*>(xbp + ((size_t)plane * B_NUM + bb + b) * 8) = v;
  }
}

// ---------------------------------------------------------------------------
// Fused dual-MFMA (R19 verbatim — best measured): W-fragments built in-LDS
// per block; bf16 hpart epilogue; 2-deep xj/dw stages.
//   MFMA1: t[fo,b] = W_p^T xi ; u = bf16(t * xj) is the B-fragment of MFMA2
//   whose A = dw[p,d] replicated over k: MFMA2 does the f-reduction AND the
//   dense fold, accumulating h[d,b] in one f32x4 per n-tile (64 batches/wave).
// grid (8, 65) = 520 blocks, block 256 = 4 waves; LDS 48 KB.
__global__ __launch_bounds__(256, 2) void fused_bilinear_dense_kernel(
    const float* __restrict__ W, const float* __restrict__ dw,
    const short* __restrict__ xbp, unsigned short* __restrict__ hpart) {
  __shared__ unsigned short wraw[PC_SZ * 1024];                  // 24 KB bf16 W [pl][e][f]
  __shared__ __align__(16) unsigned short afrag[PC_SZ * 2 * 512];// 24 KB a-frags
  const int tid  = threadIdx.x;
  const int lane = tid & 63, wv = tid >> 6;
  const int lhi = lane >> 4, llo = lane & 15;
  const int bb = blockIdx.x * 256 + wv * 64;
  const int pc = blockIdx.y;
  const int p0 = pc * PC_SZ;

  // ---- stage this chunk's 12 W matrices (48 KB f32 -> 24 KB bf16 LDS) ----
  {
    const float* Wsrc = W + (size_t)p0 * 1024;
#pragma unroll
    for (int it = 0; it < PC_SZ; ++it) {
      const int L = it * 1024 + tid * 4;
      float4 v = *reinterpret_cast<const float4*>(Wsrc + L);
      u16x4 o;
      o[0] = f2b(v.x); o[1] = f2b(v.y); o[2] = f2b(v.z); o[3] = f2b(v.w);
      *reinterpret_cast<u16x4*>(&wraw[L]) = o;                   // ds_write_b64
    }
  }
  __syncthreads();

  // ---- build per-lane A-fragments with f-PERMUTED m-rows ----
  // A-frag (16x16x32): lane l holds A[m=l&15][k=(l>>4)*8+t]; m -> fo =
  // (m>>2)*8+frag*4+(m&3), so C-row m=lhi*4+r maps to fo=lhi*8+frag*4+r.
#pragma unroll
  for (int s = 0; s < 3; ++s) {
    const int pl = wv * 3 + s;
#pragma unroll
    for (int frag = 0; frag < 2; ++frag) {
      const int fo = (llo >> 2) * 8 + frag * 4 + (llo & 3);
      bf16x8 v;
#pragma unroll
      for (int t = 0; t < 8; ++t)
        v[t] = (short)wraw[pl * 1024 + (lhi * 8 + t) * E_DIM + fo];
      *reinterpret_cast<bf16x8*>(&afrag[(pl * 2 + frag) * 512 + lane * 8]) = v;
    }
  }
  __syncthreads();

  int off[4];                                      // packed-table lane offsets
#pragma unroll
  for (int nt = 0; nt < 4; ++nt)
    off[nt] = (lhi * B_NUM + bb + nt * 16 + llo) * 8;
#define XB8(f, o) (*reinterpret_cast<const bf16x8*>(xbp + (size_t)(f) * 65536 + (o)))

  // pair walk (combinations(range(40),2) order)
  int ii[PC_SZ], jj[PC_SZ];
  {
    int i = 0;
    while ((i + 1) * (79 - (i + 1)) / 2 <= p0) ++i;
    ii[0] = i; jj[0] = i + 1 + (p0 - i * (79 - i) / 2);
  }
#pragma unroll
  for (int k = 1; k < PC_SZ; ++k) {
    int in_ = ii[k - 1], jn = jj[k - 1] + 1;
    if (jn == F_NUM) { ++in_; jn = in_ + 1; }
    ii[k] = in_; jj[k] = jn;
  }

  // xi fragments (reloaded on rare i-change only)
  bf16x8 bf[4];
#pragma unroll
  for (int nt = 0; nt < 4; ++nt) bf[nt] = XB8(ii[0], off[nt]);

  // 2-deep stages for global-memory operands (xj, dw); a-frags come from LDS
  bf16x8 sxj[2][4];
  float sdwf[2];
#pragma unroll
  for (int s = 0; s < 2; ++s) {
#pragma unroll
    for (int nt = 0; nt < 4; ++nt) sxj[s][nt] = XB8(jj[s], off[nt]);
    sdwf[s] = dw[(p0 + s) * D_DIM + llo];
  }

  f32x4 acc[4];
#pragma unroll
  for (int nt = 0; nt < 4; ++nt) acc[nt] = {0.f, 0.f, 0.f, 0.f};
  const f32x4 z = {0.f, 0.f, 0.f, 0.f};

#pragma unroll
  for (int k = 0; k < PC_SZ; ++k) {
    const int s = k & 1;
    const bf16x8 xj0 = sxj[s][0], xj1 = sxj[s][1];
    const bf16x8 xj2 = sxj[s][2], xj3 = sxj[s][3];
    const float dwf = sdwf[s];
    // refill stage s with pair k+2 (lands while k and k+1 compute)
    if (k + 2 < PC_SZ) {
#pragma unroll
      for (int nt = 0; nt < 4; ++nt) sxj[s][nt] = XB8(jj[k + 2], off[nt]);
      sdwf[s] = dw[(p0 + k + 2) * D_DIM + llo];
    }

    // a-frags from LDS (ds_read_b128, compiler-inserted lgkmcnt)
    const bf16x8 a0 = *reinterpret_cast<const bf16x8*>(&afrag[(k * 2 + 0) * 512 + lane * 8]);
    const bf16x8 a1 = *reinterpret_cast<const bf16x8*>(&afrag[(k * 2 + 1) * 512 + lane * 8]);

    // ---- compute pair k: MFMA + u-pack cluster under raised priority ----
    __builtin_amdgcn_s_setprio(1);
    f32x4 c0[4], c1[4];
#pragma unroll
    for (int nt = 0; nt < 4; ++nt) {
      c0[nt] = __builtin_amdgcn_mfma_f32_16x16x32_bf16(a0, bf[nt], z, 0, 0, 0);
      c1[nt] = __builtin_amdgcn_mfma_f32_16x16x32_bf16(a1, bf[nt], z, 0, 0, 0);
    }

    const short dwb = fcvt(dwf);
    bf16x8 a2;
#pragma unroll
    for (int t = 0; t < 8; ++t) a2[t] = dwb;

    const bf16x8 xjl[4] = {xj0, xj1, xj2, xj3};
#pragma unroll
    for (int nt = 0; nt < 4; ++nt) {
      bf16x8 u;                                    // B-frag of MFMA2
#pragma unroll
      for (int t = 0; t < 4; ++t) {
        u[t]     = fcvt(c0[nt][t] * b2f((unsigned short)xjl[nt][t]));
        u[t + 4] = fcvt(c1[nt][t] * b2f((unsigned short)xjl[nt][t + 4]));
      }
      acc[nt] = __builtin_amdgcn_mfma_f32_16x16x32_bf16(a2, u, acc[nt], 0, 0, 0);
    }
    __builtin_amdgcn_s_setprio(0);

    // xi reload on (rare) i-change, wave-uniform branch
    if (k + 1 < PC_SZ && ii[k + 1] != ii[k]) {
#pragma unroll
      for (int nt = 0; nt < 4; ++nt) bf[nt] = XB8(ii[k + 1], off[nt]);
    }
  }
#undef XB8

  // epilogue: acc (lane: b=llo, d=lhi*4+r) -> bf16 hpart[pc][b][d].
  unsigned short* hp = hpart + (size_t)pc * B_NUM * D_DIM;
#pragma unroll
  for (int nt = 0; nt < 4; ++nt) {
    u16x4 o;
    o[0] = f2b(acc[nt][0]); o[1] = f2b(acc[nt][1]);
    o[2] = f2b(acc[nt][2]); o[3] = f2b(acc[nt][3]);
    *reinterpret_cast<u16x4*>(
        hp + (size_t)(bb + nt * 16 + llo) * D_DIM + lhi * 4) = o;
  }
}

// ---------------------------------------------------------------------------
// Final: sum 65 bf16 h-partials + bias, LayerNorm. grid 64, block 256;
// thread = (b, d-pair): one uint (2 bf16) per pc -> coalesced.
__global__ __launch_bounds__(256) void reduce_ln_kernel(
    const unsigned short* __restrict__ hpart, const float* __restrict__ bias,
    const float* __restrict__ gamma, const float* __restrict__ beta,
    float* __restrict__ out) {
  const int g  = blockIdx.x * 256 + threadIdx.x;
  const int b  = g >> 3;
  const int d2 = g & 7;                            // d = 2*d2, 2*d2+1
  const uint* hp = reinterpret_cast<const uint*>(hpart) + (size_t)b * 8 + d2;

  float h0 = bias[2 * d2], h1 = bias[2 * d2 + 1];
#pragma unroll 13
  for (int pc = 0; pc < PC_N; ++pc) {
    const uint v = hp[(size_t)pc * B_NUM * 8];
    h0 += b2f((unsigned short)v);
    h1 += b2f((unsigned short)(v >> 16));
  }

  float sum = h0 + h1;
  sum += __shfl_xor(sum, 1); sum += __shfl_xor(sum, 2); sum += __shfl_xor(sum, 4);
  const float mu = sum * (1.f / D_DIM);
  const float dv0 = h0 - mu, dv1 = h1 - mu;
  float v = dv0 * dv0 + dv1 * dv1;
  v += __shfl_xor(v, 1); v += __shfl_xor(v, 2); v += __shfl_xor(v, 4);
  const float rs = rsqrtf(v * (1.f / D_DIM) + LN_EPS);

  float2 o;
  o.x = dv0 * rs * gamma[2 * d2]     + beta[2 * d2];
  o.y = dv1 * rs * gamma[2 * d2 + 1] + beta[2 * d2 + 1];
  *reinterpret_cast<float2*>(out + (size_t)b * D_DIM + 2 * d2) = o;
}

extern "C" void kernel_launch(void* const* d_in, const int* in_sizes, int n_in,
                              void* d_out, int out_size, void* d_ws, size_t ws_size,
                              hipStream_t stream) {
  const float* x     = (const float*)d_in[0];
  const float* W     = (const float*)d_in[1];
  const float* dw    = (const float*)d_in[2];
  const float* db    = (const float*)d_in[3];
  const float* gamma = (const float*)d_in[4];
  const float* beta  = (const float*)d_in[5];
  float* out = (float*)d_out;

  short*          xbp   = (short*)((char*)d_ws + XB_OFF);
  unsigned short* hpart = (unsigned short*)((char*)d_ws + HP_OFF);

  xpack_kernel<<<B_NUM / 8, 256, 0, stream>>>(x, xbp);

  dim3 gA(B_NUM / 256, PC_N);
  fused_bilinear_dense_kernel<<<gA, 256, 0, stream>>>(W, dw, xbp, hpart);

  reduce_ln_kernel<<<B_NUM * 8 / 256, 256, 0, stream>>>(hpart, db, gamma, beta, out);
}